// Round 19
// baseline (54.682 us; speedup 1.0000x reference)
//
#include <hip/hip_runtime.h>
#include <hip/hip_bf16.h>
#include <stdint.h>

#define N_TOK   4096
#define TOPK    2
#define NSORT   (N_TOK * TOPK)   // 8192
#define NEXP    8
#define DIM     1024

#define BM 128
#define BN 64
#define BK 64
#define MAXTILES 72              // sum_e ceil(cnt_e/128) <= 64 + 7; padded to 72

typedef __attribute__((ext_vector_type(8))) short bfrag;    // 8 bf16 = 4 VGPR (MFMA A/B operand)
typedef __attribute__((ext_vector_type(16))) float f32x16;  // 32x32 MFMA C/D

static __device__ __forceinline__ unsigned short f2bf(float f) {
  __hip_bfloat16 h = __float2bfloat16(f);
  return __builtin_bit_cast(unsigned short, h);
}
static __device__ __forceinline__ float bf2f(unsigned short u) {
  unsigned int v = ((unsigned int)u) << 16;
  return __builtin_bit_cast(float, v);
}

// async global->LDS, 16B per lane; lds base must be wave-uniform (HW writes base + lane*16)
static __device__ __forceinline__ void gload16(void* lds_base, const void* gsrc) {
  __builtin_amdgcn_global_load_lds(
      (const __attribute__((address_space(1))) void*)gsrc,
      (__attribute__((address_space(3))) void*)lds_base, 16, 0, 0);
}

// -- kernel 1 (fused prepass): blocks 0..2047 transpose+cast W; blocks 2048..2559 cast x;
//    block 2048 also builds the zero page + expert-aligned tile table.
__global__ __launch_bounds__(256) void k_prep_w(
    const float* __restrict__ W, const float* __restrict__ x, const int* __restrict__ eoff,
    unsigned short* __restrict__ WT, unsigned short* __restrict__ xb,
    float* __restrict__ zbuf, int* __restrict__ tbl)
{
  const int b = blockIdx.x;
  const int t = threadIdx.x;

  if (b < 2048) {
    // ---- W [e][k][n] fp32 -> WT [e][n][k] bf16, 64x64 LDS-tiled transpose ----
    __shared__ float tile[64][65];
    const int e  = b >> 8;
    const int kb = (b >> 4) & 15;
    const int nb = b & 15;
    const float* src = W + (((size_t)e * DIM) + (size_t)kb * 64) * DIM + nb * 64;
    #pragma unroll
    for (int p = 0; p < 4; ++p) {
      int q = p * 256 + t;       // 0..1023 float4-units
      int i = q >> 4;            // k-row 0..63
      int j4 = q & 15;           // float4 within row
      float4 v = *(const float4*)(src + (size_t)i * DIM + j4 * 4);
      tile[i][j4 * 4 + 0] = v.x; tile[i][j4 * 4 + 1] = v.y;
      tile[i][j4 * 4 + 2] = v.z; tile[i][j4 * 4 + 3] = v.w;
    }
    __syncthreads();
    unsigned short* dst = WT + (((size_t)e * DIM) + (size_t)nb * 64) * DIM + kb * 64;
    #pragma unroll
    for (int p = 0; p < 4; ++p) {
      int q = p * 256 + t;
      int j = q >> 4;            // n-row 0..63
      int i4 = q & 15;           // k float4
      ushort4 o;
      o.x = f2bf(tile[i4 * 4 + 0][j]);
      o.y = f2bf(tile[i4 * 4 + 1][j]);
      o.z = f2bf(tile[i4 * 4 + 2][j]);
      o.w = f2bf(tile[i4 * 4 + 3][j]);
      *(ushort4*)(dst + (size_t)j * DIM + i4 * 4) = o;
    }
  } else {
    // ---- x fp32 -> bf16 (token order); 512 blocks x 4 iters x 8 floats/thread ----
    const int c = b - 2048;
    #pragma unroll
    for (int it = 0; it < 4; ++it) {
      const size_t i = ((size_t)c * 8192) + (size_t)it * 2048 + (size_t)t * 8;
      float4 a = *(const float4*)(x + i);
      float4 v = *(const float4*)(x + i + 4);
      ushort4 oa, ob;
      oa.x = f2bf(a.x); oa.y = f2bf(a.y); oa.z = f2bf(a.z); oa.w = f2bf(a.w);
      ob.x = f2bf(v.x); ob.y = f2bf(v.y); ob.z = f2bf(v.z); ob.w = f2bf(v.w);
      *(ushort4*)(xb + i) = oa;
      *(ushort4*)(xb + i + 4) = ob;
    }
    if (c == 0) {                              // 4KB zero page + tile table
      zbuf[t] = 0.f; zbuf[256 + t] = 0.f;
      zbuf[512 + t] = 0.f; zbuf[768 + t] = 0.f;
      if (t == 0) {
        int ti = 0, prev = 0;
        for (int e = 0; e < NEXP; ++e) {
          const int end = eoff[e];
          for (int r0 = prev; r0 < end; r0 += BM) {
            tbl[ti * 2 + 0] = e;
            tbl[ti * 2 + 1] = r0;
            ++ti;
          }
          prev = end;
        }
        for (; ti < MAXTILES; ++ti) { tbl[ti * 2 + 0] = -1; tbl[ti * 2 + 1] = 0; }
      }
    }
  }
}

// swizzle: spreads 32-distinct-row column reads across banks; involution on bits 4-6 only
static __device__ __forceinline__ int swz_row(int row) {
  return ((row ^ (row >> 3)) & 7) << 4;
}

// -- kernel 2: grouped GEMM, expert-aligned tiles, 32x32x16 MFMA (2 C-tiles per wave) ----
__global__ __launch_bounds__(256, 6) void k_moe_gemm(
    const unsigned short* __restrict__ xb,   // [N_TOK][DIM] bf16 (token order)
    const unsigned short* __restrict__ WT,   // [NEXP][DIM n][DIM k] bf16
    const int* __restrict__ sei, const int* __restrict__ ssi, const int* __restrict__ kp,
    const int* __restrict__ tbl,             // [MAXTILES][2] = {expert, row_start}
    const float* __restrict__ zbuf,
    unsigned short* __restrict__ outw)       // [NSORT][DIM] bf16, rows at flat-slot index
{
  __shared__ unsigned short lA[BM * BK];   // 16 KB
  __shared__ unsigned short lB[BN * BK];   // 8 KB
  __shared__ int s_sei[BM];
  __shared__ int s_ssi[BM];
  __shared__ int s_tok[BM];

  // XCD-aware bijective swizzle (nwg=1152, 1152%8==0): contiguous 144-chunk per XCD;
  // ct-fastest decode -> the 16 ct-blocks sharing one A row-panel stay in one XCD's L2.
  const int swz = (blockIdx.x & 7) * 144 + (blockIdx.x >> 3);
  const int rt = swz >> 4;             // 0..71 tile index
  const int ct = swz & 15;             // 0..15 col tile
  const int te = tbl[rt * 2 + 0];      // tile's expert (uniform); -1 = dead tile
  if (te < 0) return;
  const int r0 = tbl[rt * 2 + 1];      // first sorted row of this tile

  const int t = threadIdx.x;
  const int lane = t & 63;
  const int w = t >> 6;                // 4 waves, 2M x 2N (64x32 tile each)
  const int wr = w >> 1;
  const int wc = w & 1;
  const int kk = kp[0];

  if (t < BM) {
    int gr = r0 + t; if (gr > NSORT - 1) gr = NSORT - 1;   // clamp: duplicate rows benign
    const int si = ssi[gr];
    s_sei[t] = sei[gr];
    s_ssi[t] = si;
    s_tok[t] = si / kk;                // source token for A-row indirection
  }
  __syncthreads();

  f32x16 acc[2];
  #pragma unroll
  for (int m = 0; m < 2; ++m)
    #pragma unroll
    for (int q = 0; q < 16; ++q)
      acc[m][q] = 0.f;

  const int l31 = lane & 31;
  const int g2  = lane >> 5;           // k-half selector within K=16 chunk

  // staging geometry (rule 21: linear LDS dest, inverse-swizzled global source)
  // A: 16 chunks of 1KB, wave owns 4w..4w+3;  B: 8 chunks, wave owns 2w..2w+1
  int rA[4], kA[4], rB[2], kB[2];
  #pragma unroll
  for (int i = 0; i < 4; ++i) {
    int o = (4 * w + i) * 1024 + lane * 16;
    int osw = o ^ swz_row(o >> 7);
    rA[i] = osw >> 7; kA[i] = osw & 127;
  }
  #pragma unroll
  for (int i = 0; i < 2; ++i) {
    int o = (2 * w + i) * 1024 + lane * 16;
    int osw = o ^ swz_row(o >> 7);
    rB[i] = osw >> 7; kB[i] = osw & 127;   // n-row 0..63
  }

  // hoisted source bases (ONCE — tile is single-expert); boundary rows -> zero page
  const char *ap[4], *bp[2];
  #pragma unroll
  for (int i = 0; i < 4; ++i)
    ap[i] = (s_sei[rA[i]] == te)
        ? (const char*)(xb + (size_t)s_tok[rA[i]] * DIM) + kA[i] : (const char*)zbuf;
  #pragma unroll
  for (int i = 0; i < 2; ++i)
    bp[i] = (const char*)(WT + (((size_t)te * DIM) + ct * BN + rB[i]) * DIM) + kB[i];

  const int rowA0 = wr * 64 + l31;       // m=0 C-tile rows
  const int rowA1 = rowA0 + 32;          // m=1
  const int rowB  = wc * 32 + l31;       // output-col rows in lB

  #pragma unroll 1
  for (int s = 0; s < DIM / BK; ++s) {   // exactly 16 K-steps, single expert
    const int koff = s * 128;            // bytes along k (4KB zero page covers +kA+16)
    #pragma unroll
    for (int i = 0; i < 4; ++i)
      gload16((char*)lA + (4 * w + i) * 1024, ap[i] + koff);
    #pragma unroll
    for (int i = 0; i < 2; ++i)
      gload16((char*)lB + (2 * w + i) * 1024, bp[i] + koff);

    __syncthreads();   // vmcnt(0) drain + barrier
    #pragma unroll
    for (int kc = 0; kc < 4; ++kc) {     // 4 x K=16 chunks; same kbyte for A and B
      const int kbyte = kc * 32 + g2 * 16;
      int oa0 = (rowA0 << 7) + kbyte; oa0 ^= swz_row(rowA0);
      int oa1 = (rowA1 << 7) + kbyte; oa1 ^= swz_row(rowA1);
      int ob  = (rowB  << 7) + kbyte; ob  ^= swz_row(rowB);
      bfrag af0 = *(const bfrag*)((const char*)lA + oa0);
      bfrag af1 = *(const bfrag*)((const char*)lA + oa1);
      bfrag bf  = *(const bfrag*)((const char*)lB + ob);
      acc[0] = __builtin_amdgcn_mfma_f32_32x32x16_bf16(af0, bf, acc[0], 0, 0, 0);
      acc[1] = __builtin_amdgcn_mfma_f32_32x32x16_bf16(af1, bf, acc[1], 0, 0, 0);
    }
    __syncthreads();   // compute done before next stage overwrites LDS
  }

  // epilogue: 32x32 C/D map (m74/m101): col = lane&31, row = (reg&3)+8*(reg>>2)+4*(lane>>5)
  #pragma unroll
  for (int m = 0; m < 2; ++m) {
    #pragma unroll
    for (int q = 0; q < 16; ++q) {
      const int rl = wr * 64 + m * 32 + (q & 3) + 8 * (q >> 2) + 4 * g2;
      if (s_sei[rl] != te) continue;   // neighbor expert's rows: covered by its own tile
      const int orow = s_ssi[rl];
      outw[(size_t)orow * DIM + ct * BN + wc * 32 + l31] = f2bf(acc[m][q]);
    }
  }
}

// ---------------- kernel 3: gate-weighted pair combine -> fp32 out ----------------------
__global__ __launch_bounds__(256) void k_combine(
    const unsigned short* __restrict__ outw, const float* __restrict__ gates,
    const int* __restrict__ kp, float* __restrict__ out)
{
  const int tk = blockIdx.x;     // token
  const int t = threadIdx.x;     // 256 threads x 4 floats
  const int kk = kp[0];
  float4 o = {0.f, 0.f, 0.f, 0.f};
  for (int s = 0; s < kk; ++s) {
    const float gte = gates[tk * kk + s];
    ushort4 a = ((const ushort4*)(outw + ((size_t)tk * kk + s) * DIM))[t];
    o.x += gte * bf2f(a.x);
    o.y += gte * bf2f(a.y);
    o.z += gte * bf2f(a.z);
    o.w += gte * bf2f(a.w);
  }
  ((float4*)(out + (size_t)tk * DIM))[t] = o;
}

extern "C" void kernel_launch(void* const* d_in, const int* in_sizes, int n_in,
                              void* d_out, int out_size, void* d_ws, size_t ws_size,
                              hipStream_t stream)
{
  const float* x     = (const float*)d_in[0];
  const float* W     = (const float*)d_in[1];
  const float* gates = (const float*)d_in[2];
  const int* kp      = (const int*)d_in[3];
  const int* sei     = (const int*)d_in[4];
  const int* ssi     = (const int*)d_in[5];
  const int* eoff    = (const int*)d_in[7];   // expert_offsets (cumsum of counts)

  const size_t MB = 1024 * 1024;
  if (ws_size < 40 * MB + 8192) return;   // 40MB scratch + 4KB zero page + tile table

  char* ws = (char*)d_ws;
  unsigned short* xb   = (unsigned short*)(ws);              // 8  MB: bf16 x (token order)
  unsigned short* WT   = (unsigned short*)(ws + 8 * MB);     // 16 MB: bf16 W^T
  unsigned short* outw = (unsigned short*)(ws + 24 * MB);    // 16 MB: bf16 out_flat
  float* zbuf          = (float*)(ws + 40 * MB);             // 4 KB zero page
  int* tbl             = (int*)(ws + 40 * MB + 4096);        // 576 B tile table

  k_prep_w<<<2560, 256, 0, stream>>>(W, x, eoff, WT, xb, zbuf, tbl);
  k_moe_gemm<<<MAXTILES * (DIM / BN), 256, 0, stream>>>(
      xb, WT, sei, ssi, kp, tbl, zbuf, outw);
  k_combine<<<N_TOK, 256, 0, stream>>>(outw, gates, kp, (float*)d_out);
}

// Round 20
// 51.611 us; speedup vs baseline: 1.0595x; 1.0595x over previous
//
#include <hip/hip_runtime.h>
#include <hip/hip_bf16.h>
#include <stdint.h>

#define N_TOK   4096
#define TOPK    2
#define NSORT   (N_TOK * TOPK)   // 8192
#define NEXP    8
#define DIM     1024

#define BM 128
#define BN 64
#define BK 64
#define MAXTILES 72              // sum_e ceil(cnt_e/128) <= 64 + 7; padded to 72

typedef __attribute__((ext_vector_type(8))) short bfrag;    // 8 bf16 = 4 VGPR (MFMA A/B operand)
typedef __attribute__((ext_vector_type(4))) float f32x4;    // MFMA C/D

static __device__ __forceinline__ unsigned short f2bf(float f) {
  __hip_bfloat16 h = __float2bfloat16(f);
  return __builtin_bit_cast(unsigned short, h);
}
static __device__ __forceinline__ float bf2f(unsigned short u) {
  unsigned int v = ((unsigned int)u) << 16;
  return __builtin_bit_cast(float, v);
}

// async global->LDS, 16B per lane; lds base must be wave-uniform (HW writes base + lane*16)
static __device__ __forceinline__ void gload16(void* lds_base, const void* gsrc) {
  __builtin_amdgcn_global_load_lds(
      (const __attribute__((address_space(1))) void*)gsrc,
      (__attribute__((address_space(3))) void*)lds_base, 16, 0, 0);
}

// -- kernel 1 (fused prepass): blocks 0..2047 transpose+cast W; blocks 2048..2559 cast x;
//    block 2048 also builds the zero page + expert-aligned tile table.
__global__ __launch_bounds__(256) void k_prep_w(
    const float* __restrict__ W, const float* __restrict__ x, const int* __restrict__ eoff,
    unsigned short* __restrict__ WT, unsigned short* __restrict__ xb,
    float* __restrict__ zbuf, int* __restrict__ tbl)
{
  const int b = blockIdx.x;
  const int t = threadIdx.x;

  if (b < 2048) {
    // ---- W [e][k][n] fp32 -> WT [e][n][k] bf16, 64x64 LDS-tiled transpose ----
    __shared__ float tile[64][65];
    const int e  = b >> 8;
    const int kb = (b >> 4) & 15;
    const int nb = b & 15;
    const float* src = W + (((size_t)e * DIM) + (size_t)kb * 64) * DIM + nb * 64;
    #pragma unroll
    for (int p = 0; p < 4; ++p) {
      int q = p * 256 + t;       // 0..1023 float4-units
      int i = q >> 4;            // k-row 0..63
      int j4 = q & 15;           // float4 within row
      float4 v = *(const float4*)(src + (size_t)i * DIM + j4 * 4);
      tile[i][j4 * 4 + 0] = v.x; tile[i][j4 * 4 + 1] = v.y;
      tile[i][j4 * 4 + 2] = v.z; tile[i][j4 * 4 + 3] = v.w;
    }
    __syncthreads();
    unsigned short* dst = WT + (((size_t)e * DIM) + (size_t)nb * 64) * DIM + kb * 64;
    #pragma unroll
    for (int p = 0; p < 4; ++p) {
      int q = p * 256 + t;
      int j = q >> 4;            // n-row 0..63
      int i4 = q & 15;           // k float4
      ushort4 o;
      o.x = f2bf(tile[i4 * 4 + 0][j]);
      o.y = f2bf(tile[i4 * 4 + 1][j]);
      o.z = f2bf(tile[i4 * 4 + 2][j]);
      o.w = f2bf(tile[i4 * 4 + 3][j]);
      *(ushort4*)(dst + (size_t)j * DIM + i4 * 4) = o;
    }
  } else {
    // ---- x fp32 -> bf16 (token order); 512 blocks x 4 iters x 8 floats/thread ----
    const int c = b - 2048;
    #pragma unroll
    for (int it = 0; it < 4; ++it) {
      const size_t i = ((size_t)c * 8192) + (size_t)it * 2048 + (size_t)t * 8;
      float4 a = *(const float4*)(x + i);
      float4 v = *(const float4*)(x + i + 4);
      ushort4 oa, ob;
      oa.x = f2bf(a.x); oa.y = f2bf(a.y); oa.z = f2bf(a.z); oa.w = f2bf(a.w);
      ob.x = f2bf(v.x); ob.y = f2bf(v.y); ob.z = f2bf(v.z); ob.w = f2bf(v.w);
      *(ushort4*)(xb + i) = oa;
      *(ushort4*)(xb + i + 4) = ob;
    }
    if (c == 0) {                              // 4KB zero page + tile table
      zbuf[t] = 0.f; zbuf[256 + t] = 0.f;
      zbuf[512 + t] = 0.f; zbuf[768 + t] = 0.f;
      if (t == 0) {
        int ti = 0, prev = 0;
        for (int e = 0; e < NEXP; ++e) {
          const int end = eoff[e];
          for (int r0 = prev; r0 < end; r0 += BM) {
            tbl[ti * 2 + 0] = e;
            tbl[ti * 2 + 1] = r0;
            ++ti;
          }
          prev = end;
        }
        for (; ti < MAXTILES; ++ti) { tbl[ti * 2 + 0] = -1; tbl[ti * 2 + 1] = 0; }
      }
    }
  }
}

// -- kernel 2: grouped GEMM, r7 geometry, EXPERT-ALIGNED tiles (uniform expert per tile) --
__global__ __launch_bounds__(256, 6) void k_moe_gemm(
    const unsigned short* __restrict__ xb,   // [N_TOK][DIM] bf16 (token order)
    const unsigned short* __restrict__ WT,   // [NEXP][DIM n][DIM k] bf16
    const int* __restrict__ sei, const int* __restrict__ ssi, const int* __restrict__ kp,
    const int* __restrict__ tbl,             // [MAXTILES][2] = {expert, row_start}
    const float* __restrict__ zbuf,
    unsigned short* __restrict__ outw)       // [NSORT][DIM] bf16, rows at flat-slot index
{
  __shared__ unsigned short lA[BM * BK];   // 16 KB
  __shared__ unsigned short lB[BN * BK];   // 8 KB
  __shared__ int s_sei[BM];
  __shared__ int s_ssi[BM];
  __shared__ int s_tok[BM];

  // XCD-aware bijective swizzle (nwg=1152, 1152%8==0): contiguous 144-chunk per XCD;
  // ct-fastest decode -> the 16 ct-blocks sharing one A row-panel stay in one XCD's L2.
  const int swz = (blockIdx.x & 7) * 144 + (blockIdx.x >> 3);
  const int rt = swz >> 4;             // 0..71 tile index
  const int ct = swz & 15;             // 0..15 col tile
  const int te = tbl[rt * 2 + 0];      // tile's expert (uniform); -1 = dead tile
  if (te < 0) return;
  const int r0 = tbl[rt * 2 + 1];      // first sorted row of this tile

  const int t = threadIdx.x;
  const int lane = t & 63;
  const int w = t >> 6;                // 4 waves, 2M x 2N (64x32 tile each)
  const int wr = w >> 1;
  const int wc = w & 1;
  const int kk = kp[0];

  if (t < BM) {
    int gr = r0 + t; if (gr > NSORT - 1) gr = NSORT - 1;   // clamp: duplicate rows benign
    const int si = ssi[gr];
    s_sei[t] = sei[gr];
    s_ssi[t] = si;
    s_tok[t] = si / kk;                // source token for A-row indirection
  }
  __syncthreads();

  f32x4 acc[4][2];
  #pragma unroll
  for (int m = 0; m < 4; ++m)
    #pragma unroll
    for (int n = 0; n < 2; ++n)
      acc[m][n] = (f32x4){0.f, 0.f, 0.f, 0.f};

  const int g = lane >> 4;
  const int r = lane & 15;

  // staging geometry (rule 21: linear LDS dest, inverse-swizzled global source)
  // A: 16 chunks of 1KB, wave owns 4w..4w+3;  B: 8 chunks, wave owns 2w..2w+1
  int rA[4], kA[4], rB[2], kB[2];
  #pragma unroll
  for (int i = 0; i < 4; ++i) {
    int o = (4 * w + i) * 1024 + lane * 16;
    int osw = o ^ (((o >> 7) & 7) << 4);
    rA[i] = osw >> 7; kA[i] = osw & 127;
  }
  #pragma unroll
  for (int i = 0; i < 2; ++i) {
    int o = (2 * w + i) * 1024 + lane * 16;
    int osw = o ^ (((o >> 7) & 7) << 4);
    rB[i] = osw >> 7; kB[i] = osw & 127;   // n-row 0..63
  }

  // hoisted source bases (ONCE — tile is single-expert); boundary rows -> zero page
  const char *ap[4], *bp[2];
  #pragma unroll
  for (int i = 0; i < 4; ++i)
    ap[i] = (s_sei[rA[i]] == te)
        ? (const char*)(xb + (size_t)s_tok[rA[i]] * DIM) + kA[i] : (const char*)zbuf;
  #pragma unroll
  for (int i = 0; i < 2; ++i)
    bp[i] = (const char*)(WT + (((size_t)te * DIM) + ct * BN + rB[i]) * DIM) + kB[i];

  #pragma unroll 1
  for (int s = 0; s < DIM / BK; ++s) {   // exactly 16 K-steps, single expert
    const int koff = s * 128;            // bytes along k (4KB zero page covers +kA+16)
    #pragma unroll
    for (int i = 0; i < 4; ++i)
      gload16((char*)lA + (4 * w + i) * 1024, ap[i] + koff);
    #pragma unroll
    for (int i = 0; i < 2; ++i)
      gload16((char*)lB + (2 * w + i) * 1024, bp[i] + koff);

    __syncthreads();   // vmcnt(0) drain + barrier
    #pragma unroll
    for (int kh = 0; kh < 2; ++kh) {
      const int kbyte = (kh * 32 + 8 * g) * 2;   // same k-slot for A and B (positional symmetry)
      bfrag af[4], bfv[2];
      #pragma unroll
      for (int m = 0; m < 4; ++m) {
        const int row = wr * 64 + m * 16 + r;
        int o = (row << 7) + kbyte;
        o ^= ((row & 7) << 4);
        af[m] = *(const bfrag*)((const char*)lA + o);
      }
      #pragma unroll
      for (int n = 0; n < 2; ++n) {
        const int nn = wc * 32 + n * 16 + r;
        int o = (nn << 7) + kbyte;
        o ^= ((nn & 7) << 4);
        bfv[n] = *(const bfrag*)((const char*)lB + o);
      }
      #pragma unroll
      for (int m = 0; m < 4; ++m)
        #pragma unroll
        for (int n = 0; n < 2; ++n)
          acc[m][n] = __builtin_amdgcn_mfma_f32_16x16x32_bf16(af[m], bfv[n], acc[m][n], 0, 0, 0);
    }
    __syncthreads();   // compute done before next stage overwrites LDS
  }

  // epilogue: C/D map col = lane&15, row = (lane>>4)*4 + reg; scatter rows by ssi (bf16);
  // skip rows belonging to the neighboring expert (they're covered by that expert's tile)
  #pragma unroll
  for (int m = 0; m < 4; ++m) {
    #pragma unroll
    for (int q = 0; q < 4; ++q) {
      const int rl = wr * 64 + m * 16 + g * 4 + q;
      if (s_sei[rl] != te) continue;
      const int orow = s_ssi[rl];
      unsigned short* od = outw + (size_t)orow * DIM + ct * BN + wc * 32 + r;
      #pragma unroll
      for (int n = 0; n < 2; ++n)
        od[n * 16] = f2bf(acc[m][n][q]);
    }
  }
}

// ---------------- kernel 3: gate-weighted pair combine -> fp32 out ----------------------
__global__ __launch_bounds__(256) void k_combine(
    const unsigned short* __restrict__ outw, const float* __restrict__ gates,
    const int* __restrict__ kp, float* __restrict__ out)
{
  const int tk = blockIdx.x;     // token
  const int t = threadIdx.x;     // 256 threads x 4 floats
  const int kk = kp[0];
  float4 o = {0.f, 0.f, 0.f, 0.f};
  for (int s = 0; s < kk; ++s) {
    const float gte = gates[tk * kk + s];
    ushort4 a = ((const ushort4*)(outw + ((size_t)tk * kk + s) * DIM))[t];
    o.x += gte * bf2f(a.x);
    o.y += gte * bf2f(a.y);
    o.z += gte * bf2f(a.z);
    o.w += gte * bf2f(a.w);
  }
  ((float4*)(out + (size_t)tk * DIM))[t] = o;
}

extern "C" void kernel_launch(void* const* d_in, const int* in_sizes, int n_in,
                              void* d_out, int out_size, void* d_ws, size_t ws_size,
                              hipStream_t stream)
{
  const float* x     = (const float*)d_in[0];
  const float* W     = (const float*)d_in[1];
  const float* gates = (const float*)d_in[2];
  const int* kp      = (const int*)d_in[3];
  const int* sei     = (const int*)d_in[4];
  const int* ssi     = (const int*)d_in[5];
  const int* eoff    = (const int*)d_in[7];   // expert_offsets (cumsum of counts)

  const size_t MB = 1024 * 1024;
  if (ws_size < 40 * MB + 8192) return;   // 40MB scratch + 4KB zero page + tile table

  char* ws = (char*)d_ws;
  unsigned short* xb   = (unsigned short*)(ws);              // 8  MB: bf16 x (token order)
  unsigned short* WT   = (unsigned short*)(ws + 8 * MB);     // 16 MB: bf16 W^T
  unsigned short* outw = (unsigned short*)(ws + 24 * MB);    // 16 MB: bf16 out_flat
  float* zbuf          = (float*)(ws + 40 * MB);             // 4 KB zero page
  int* tbl             = (int*)(ws + 40 * MB + 4096);        // 576 B tile table

  k_prep_w<<<2560, 256, 0, stream>>>(W, x, eoff, WT, xb, zbuf, tbl);
  k_moe_gemm<<<MAXTILES * (DIM / BN), 256, 0, stream>>>(
      xb, WT, sei, ssi, kp, tbl, zbuf, outw);
  k_combine<<<N_TOK, 256, 0, stream>>>(outw, gates, kp, (float*)d_out);
}